// Round 3
// baseline (341.019 us; speedup 1.0000x reference)
//
#include <hip/hip_runtime.h>

#define SIDE 96
#define NN 9216            // SIDE*SIDE
#define BATCH 32
#define KC 32              // k-chunk staged in LDS per wave
#define CPT 4              // columns per thread
#define COLS 256           // columns per block (64 lanes * CPT)

__device__ __forceinline__ float clamp01(float v) {
    // custom_sigmoid with THETA=0: where(x<0, 0, x) then min(,1)
    return fminf(fmaxf(v, 0.0f), 1.0f);
}

// xt[j*32 + b] = x[b*NN + j]
__global__ __launch_bounds__(256) void k_transpose(const float* __restrict__ x,
                                                   float* __restrict__ xt) {
    int idx = blockIdx.x * 256 + threadIdx.x;     // over NN*BATCH (exact multiple)
    int j = idx >> 5;
    int b = idx & 31;
    xt[idx] = x[(size_t)b * NN + j];
}

// Partial GEMM: part[s][j][b] = sum_{k in slice s} at[k][b] * W[k][j]
// Block: 256 threads = 4 waves, COLS=256 columns (lane owns 4 consecutive -> one
// dwordx4 W load per k). The 4 waves split the k-slice 4 ways (per-wave private
// LDS staging, no block barrier in the main loop); cross-wave reduce at the end.
__global__ __launch_bounds__(256, 3) void k_gemm_part(
    const float* __restrict__ W,      // [NN][NN] row-major (k-major)
    const float* __restrict__ at,     // [NN][BATCH]
    float* __restrict__ part,         // [S][NN][BATCH]
    int slice_len)                    // multiple of 4*KC
{
    __shared__ float sa[4][KC * BATCH];       // 16 KB: per-wave activation chunk
    __shared__ float sred[3][8 * 64 * 4];     // 24 KB: cross-wave reduce buffer

    const int wave = threadIdx.x >> 6;
    const int lane = threadIdx.x & 63;
    const int ncolblk = NN / COLS;            // 36
    const int cb = blockIdx.x % ncolblk;
    const int s  = blockIdx.x / ncolblk;
    const int j0 = cb * COLS + lane * CPT;    // first of 4 consecutive cols
    const int wk = slice_len >> 2;            // per-wave k extent
    const size_t k0 = (size_t)s * slice_len + (size_t)wave * wk;

    const float* Wp = W + k0 * NN + j0;
    const float* ap = at + k0 * BATCH;
    float* sw = sa[wave];

    float acc[CPT][BATCH];
#pragma unroll
    for (int c = 0; c < CPT; ++c)
#pragma unroll
        for (int b = 0; b < BATCH; ++b) acc[c][b] = 0.0f;

    for (int kk = 0; kk < wk; kk += KC) {
        {   // per-wave stage: KC*BATCH = 1024 floats = 256 float4, 4 per lane
            const float4* src = (const float4*)(ap + (size_t)kk * BATCH);
            float4* dst = (float4*)sw;
#pragma unroll
            for (int g = 0; g < 4; ++g)
                dst[g * 64 + lane] = src[g * 64 + lane];
        }
        // drain ds_writes before same-wave cross-lane ds_reads (no block barrier)
        asm volatile("s_waitcnt lgkmcnt(0)" ::: "memory");
        __builtin_amdgcn_wave_barrier();

        const float* wrow = Wp + (size_t)kk * NN;
#pragma unroll 2
        for (int u = 0; u < KC; ++u) {
            const float4 wv = *(const float4*)(wrow + (size_t)u * NN);
            const float4* a4 = (const float4*)(sw + u * BATCH);
#pragma unroll
            for (int q = 0; q < 8; ++q) {
                const float4 av = a4[q];
#pragma unroll
                for (int c = 0; c < CPT; ++c) {
                    const float wc = (c == 0) ? wv.x : (c == 1) ? wv.y
                                   : (c == 2) ? wv.z : wv.w;
                    acc[c][4*q+0] = fmaf(av.x, wc, acc[c][4*q+0]);
                    acc[c][4*q+1] = fmaf(av.y, wc, acc[c][4*q+1]);
                    acc[c][4*q+2] = fmaf(av.z, wc, acc[c][4*q+2]);
                    acc[c][4*q+3] = fmaf(av.w, wc, acc[c][4*q+3]);
                }
            }
        }
    }

    // cross-wave reduction, one column-group at a time (keeps LDS at 24 KB)
#pragma unroll
    for (int c = 0; c < CPT; ++c) {
        if (wave > 0) {
            float4* dst = (float4*)sred[wave - 1];
#pragma unroll
            for (int q = 0; q < 8; ++q)
                dst[q * 64 + lane] = make_float4(acc[c][4*q+0], acc[c][4*q+1],
                                                 acc[c][4*q+2], acc[c][4*q+3]);
        }
        __syncthreads();
        if (wave == 0) {
            const float4* r0 = (const float4*)sred[0];
            const float4* r1 = (const float4*)sred[1];
            const float4* r2 = (const float4*)sred[2];
            float* pbase = part + ((size_t)s * NN + (size_t)(j0 + c)) * BATCH;
#pragma unroll
            for (int q = 0; q < 8; ++q) {
                const float4 v0 = r0[q * 64 + lane];
                const float4 v1 = r1[q * 64 + lane];
                const float4 v2 = r2[q * 64 + lane];
                float4 o;
                o.x = acc[c][4*q+0] + v0.x + v1.x + v2.x;
                o.y = acc[c][4*q+1] + v0.y + v1.y + v2.y;
                o.z = acc[c][4*q+2] + v0.z + v1.z + v2.z;
                o.w = acc[c][4*q+3] + v0.w + v1.w + v2.w;
                *(float4*)(pbase + 4 * q) = o;
            }
        }
        __syncthreads();
    }
}

// aff_t[idx] = clamp01( sum_s part[s][idx] )
__global__ __launch_bounds__(256) void k_reduce_aff(const float* __restrict__ part,
                                                    float* __restrict__ aff_t,
                                                    int nslices) {
    int idx = blockIdx.x * 256 + threadIdx.x;
    float v = 0.0f;
    for (int s = 0; s < nslices; ++s)
        v += part[(size_t)s * NN * BATCH + idx];
    aff_t[idx] = clamp01(v);
}

// Fused epilogue: reduce inhibitory partials, sparse excitatory gather
// (13 compile-time-known offsets of the radius-2 circular mask), combine.
__global__ __launch_bounds__(256) void k_combine(
    const float* __restrict__ part,   // inhibitory partials [S][NN][BATCH]
    const float* __restrict__ aff_t,  // [NN][BATCH], already clamped
    const float* __restrict__ We,     // [NN][NN]
    float* __restrict__ out,          // [BATCH][NN]
    int nslices)
{
    int idx = blockIdx.x * 256 + threadIdx.x;
    int j = idx >> 5;
    int b = idx & 31;

    float inh = 0.0f;
    for (int s = 0; s < nslices; ++s)
        inh += part[(size_t)s * NN * BATCH + idx];
    inh = clamp01(inh);

    int mx = j / SIDE;
    int my = j - mx * SIDE;

    // offsets with dx*dx+dy*dy <= 4 (EXC_RADIUS=2): 13 taps
    const int dxs[13] = {-2,-1,-1,-1, 0, 0, 0, 0, 0, 1, 1, 1, 2};
    const int dys[13] = { 0,-1, 0, 1,-2,-1, 0, 1, 2,-1, 0, 1, 0};

    float exc = 0.0f;
#pragma unroll
    for (int t = 0; t < 13; ++t) {
        int x = mx + dxs[t];
        int y = my + dys[t];
        if ((unsigned)x < SIDE && (unsigned)y < SIDE) {
            int i = x * SIDE + y;
            float w = We[(size_t)i * NN + j];       // broadcast within half-wave
            exc = fmaf(aff_t[(size_t)i * BATCH + b], w, exc);
        }
    }
    exc = clamp01(exc);

    float a = aff_t[idx];
    out[(size_t)b * NN + j] = clamp01(a + 0.2f * exc - 0.4f * inh);
}

extern "C" void kernel_launch(void* const* d_in, const int* in_sizes, int n_in,
                              void* d_out, int out_size, void* d_ws, size_t ws_size,
                              hipStream_t stream) {
    const float* x  = (const float*)d_in[0];  // [32][9216]
    const float* Wr = (const float*)d_in[1];  // [9216][9216]
    const float* We = (const float*)d_in[2];  // [9216][9216] sparse (radius 2)
    const float* Wi = (const float*)d_in[3];  // [9216][9216]
    float* out = (float*)d_out;               // [32][9216]

    float* xt   = (float*)d_ws;                        // NN*BATCH floats
    float* afft = xt + (size_t)NN * BATCH;             // NN*BATCH floats
    float* part = afft + (size_t)NN * BATCH;           // S*NN*BATCH floats (shared
                                                       // by both GEMMs sequentially)

    // Split-K factor: slice_len = NN/S must stay a multiple of 4*KC=128.
    // S=24 -> slice 384 (per wave 96 = 3 KC-chunks), 864 blocks. Halving
    // fallback (24->12->6->3) preserves divisibility.
    size_t base_bytes = (size_t)NN * BATCH * 2 * sizeof(float);
    int S = 24;
    while (S > 1 && base_bytes + (size_t)S * NN * BATCH * sizeof(float) > ws_size)
        S >>= 1;
    int slice_len = NN / S;

    dim3 blk(256);
    dim3 grid_eb(NN * BATCH / 256);   // 1152
    dim3 grid_gm((NN / COLS) * S);    // 36*S

    k_transpose <<<grid_eb, blk, 0, stream>>>(x, xt);
    k_gemm_part <<<grid_gm, blk, 0, stream>>>(Wr, xt, part, slice_len);
    k_reduce_aff<<<grid_eb, blk, 0, stream>>>(part, afft, S);
    k_gemm_part <<<grid_gm, blk, 0, stream>>>(Wi, afft, part, slice_len);
    k_combine   <<<grid_eb, blk, 0, stream>>>(part, afft, We, out, S);
}